// Round 1
// baseline (863.358 us; speedup 1.0000x reference)
//
#include <hip/hip_runtime.h>
#include <math.h>

#define N_TOK 16384
#define H_DIM 2048
#define E_EXP 64
#define TH    128
#define RPW   8
#define RPB   32

// d_out layout (float32, reference return order)
#define OUT_IDX   0
#define OUT_W     (N_TOK * 2)
#define OUT_LOSS  (N_TOK * 4)
#define OUT_FRAC  (N_TOK * 4 + 1)
#define OUT_PROBS (N_TOK * 4 + 1 + E_EXP)

// ws layout (floats): [0..63] prob sums, [64..127] counts, [128] list count (int), [192..] fixup row list (int)
#define WS_LIST_OFF 192

__global__ void zero_ws_kernel(float* __restrict__ ws) {
    int t = threadIdx.x;
    if (t < WS_LIST_OFF) ws[t] = 0.0f;
}

__global__ __launch_bounds__(256, 2) void router_kernel(
    const float* __restrict__ x, const float* __restrict__ W,
    float* __restrict__ out, float* __restrict__ ws, int cap) {
    __shared__ float wl[E_EXP * 129];
    const int tid  = threadIdx.x;
    const int lane = tid & 63;
    const int wid  = tid >> 6;
    const int rowBase = __builtin_amdgcn_readfirstlane((int)(blockIdx.x * RPB + wid * RPW));

    float acc[RPW];
#pragma unroll
    for (int r = 0; r < RPW; ++r) acc[r] = 0.0f;

    for (int t = 0; t < H_DIM / TH; ++t) {
        const int h0 = t * TH;
        __syncthreads();
#pragma unroll
        for (int i = 0; i < (E_EXP * TH) / 256; ++i) {
            int idx = i * 256 + tid;
            int e = idx >> 7;          // TH = 128
            int k = idx & (TH - 1);
            wl[e * 129 + k] = W[e * H_DIM + h0 + k];
        }
        __syncthreads();
        const float* xb = x + h0;
#pragma unroll 2
        for (int kc = 0; kc < TH; kc += 4) {
            float4 xv[RPW];
#pragma unroll
            for (int r = 0; r < RPW; ++r)
                xv[r] = *(const float4*)(xb + (size_t)(rowBase + r) * H_DIM + kc);
#pragma unroll
            for (int kk = 0; kk < 4; ++kk) {
                float w = wl[lane * 129 + kc + kk];
#pragma unroll
                for (int r = 0; r < RPW; ++r)
                    acc[r] = fmaf(((const float*)&xv[r])[kk], w, acc[r]);
            }
        }
    }

    // ---- epilogue: per-row softmax + top-2 + reductions ----
    float psum = 0.0f;
    int   pcnt = 0;
    float* outIdx = out + OUT_IDX;
    float* outW   = out + OUT_W;
    float* outP   = out + OUT_PROBS;
    int* li   = (int*)(ws + 128);
    int* list = (int*)(ws + WS_LIST_OFF);

#pragma unroll 1
    for (int r = 0; r < RPW; ++r) {
        const int row = rowBase + r;
        const float v = acc[r];

        // top-1 (value, lowest index on tie)
        float bv = v; int bi = lane;
#pragma unroll
        for (int m = 32; m >= 1; m >>= 1) {
            float ov = __shfl_xor(bv, m);
            int   oi = __shfl_xor(bi, m);
            if (ov > bv || (ov == bv && oi < bi)) { bv = ov; bi = oi; }
        }
        const float v1 = bv; const int i1 = bi;

        // top-2
        bv = (lane == i1) ? -__builtin_inff() : v; bi = lane;
#pragma unroll
        for (int m = 32; m >= 1; m >>= 1) {
            float ov = __shfl_xor(bv, m);
            int   oi = __shfl_xor(bi, m);
            if (ov > bv || (ov == bv && oi < bi)) { bv = ov; bi = oi; }
        }
        const float v2 = bv; const int i2 = bi;

        // third-best value (for the selection-boundary gap)
        float t3 = (lane == i1 || lane == i2) ? -__builtin_inff() : v;
#pragma unroll
        for (int m = 32; m >= 1; m >>= 1) t3 = fmaxf(t3, __shfl_xor(t3, m));

        // full softmax over 64 experts
        float ee = __expf(v - v1);
        float s = ee;
#pragma unroll
        for (int m = 32; m >= 1; m >>= 1) s += __shfl_xor(s, m);
        float prob = ee / s;
        outP[(size_t)row * E_EXP + lane] = prob;
        psum += prob;
        pcnt += (lane == i1 ? 1 : 0) + (lane == i2 ? 1 : 0);

        if (lane == 0) {
            float ew = __expf(v2 - v1);
            outIdx[row * 2]     = (float)i1;
            outIdx[row * 2 + 1] = (float)i2;
            outW[row * 2]       = 1.0f / (1.0f + ew);
            outW[row * 2 + 1]   = ew / (1.0f + ew);
            // near-tie at top-1/2 ordering or top-2/3 selection boundary -> fp64 fixup
            if (fminf(v1 - v2, v2 - t3) < 4e-6f) {
                int slot = atomicAdd(li, 1);
                if (slot < cap) list[slot] = row;
            }
        }
    }
    atomicAdd(&ws[lane], psum);
    atomicAdd(&ws[64 + lane], (float)pcnt);
}

// fp64 recompute of flagged near-tie rows; overwrites indices + weights exactly.
__global__ void fixup_kernel(const float* __restrict__ x, const float* __restrict__ W,
                             float* __restrict__ out, float* __restrict__ ws, int cap) {
    const int lane = threadIdx.x;  // 64 threads
    const int* li   = (const int*)(ws + 128);
    const int* list = (const int*)(ws + WS_LIST_OFF);
    int cnt = *li;
    if (cnt > cap) cnt = cap;
    for (int j = blockIdx.x; j < cnt; j += gridDim.x) {
        const int row = list[j];
        const float* xr = x + (size_t)row * H_DIM;
        float xv[H_DIM / 64];
#pragma unroll
        for (int i = 0; i < H_DIM / 64; ++i) xv[i] = xr[lane + 64 * i];  // coalesced

        double myLogit = 0.0;
        for (int e = 0; e < E_EXP; ++e) {
            const float* wr = W + (size_t)e * H_DIM;
            double a0 = 0.0, a1 = 0.0;
#pragma unroll
            for (int i = 0; i < H_DIM / 64; i += 2) {
                a0 += (double)xv[i]     * (double)wr[lane + 64 * i];
                a1 += (double)xv[i + 1] * (double)wr[lane + 64 * (i + 1)];
            }
            double a = a0 + a1;
#pragma unroll
            for (int m = 32; m >= 1; m >>= 1) a += __shfl_xor(a, m);
            if (lane == e) myLogit = a;
        }
        double bv = myLogit; int bi = lane;
#pragma unroll
        for (int m = 32; m >= 1; m >>= 1) {
            double ov = __shfl_xor(bv, m);
            int    oi = __shfl_xor(bi, m);
            if (ov > bv || (ov == bv && oi < bi)) { bv = ov; bi = oi; }
        }
        double v1 = bv; int i1 = bi;
        bv = (lane == i1) ? -1.0e300 : myLogit; bi = lane;
#pragma unroll
        for (int m = 32; m >= 1; m >>= 1) {
            double ov = __shfl_xor(bv, m);
            int    oi = __shfl_xor(bi, m);
            if (ov > bv || (ov == bv && oi < bi)) { bv = ov; bi = oi; }
        }
        double v2 = bv; int i2 = bi;
        if (lane == 0) {
            double ew = exp(v2 - v1);
            out[OUT_IDX + row * 2]     = (float)i1;
            out[OUT_IDX + row * 2 + 1] = (float)i2;
            out[OUT_W + row * 2]       = (float)(1.0 / (1.0 + ew));
            out[OUT_W + row * 2 + 1]   = (float)(ew / (1.0 + ew));
        }
    }
}

__global__ void finalize_kernel(float* __restrict__ out, const float* __restrict__ ws) {
    const int lane = threadIdx.x;  // 64 threads
    float f = ws[64 + lane] * (1.0f / (float)N_TOK);
    float p = ws[lane]      * (1.0f / (float)N_TOK);
    out[OUT_FRAC + lane] = f;
    float prod = f * p;
#pragma unroll
    for (int m = 32; m >= 1; m >>= 1) prod += __shfl_xor(prod, m);
    if (lane == 0) out[OUT_LOSS] = (float)E_EXP * prod;
}

extern "C" void kernel_launch(void* const* d_in, const int* in_sizes, int n_in,
                              void* d_out, int out_size, void* d_ws, size_t ws_size,
                              hipStream_t stream) {
    const float* x = (const float*)d_in[0];
    const float* W = (const float*)d_in[1];
    float* out = (float*)d_out;
    float* ws  = (float*)d_ws;

    size_t ws_floats = ws_size / 4;
    int cap = 0;
    if (ws_floats > WS_LIST_OFF) {
        size_t c = ws_floats - WS_LIST_OFF;
        cap = (c > (size_t)N_TOK) ? N_TOK : (int)c;
    }

    zero_ws_kernel<<<1, 256, 0, stream>>>(ws);
    router_kernel<<<N_TOK / RPB, 256, 0, stream>>>(x, W, out, ws, cap);
    fixup_kernel<<<256, 64, 0, stream>>>(x, W, out, ws, cap);
    finalize_kernel<<<1, 64, 0, stream>>>(out, ws);
}